// Round 9
// baseline (2220.174 us; speedup 1.0000x reference)
//
#include <hip/hip_runtime.h>
#include <math.h>

#define NB 4
#define DIMM 256
#define DSTATE 16
#define DCONV 4
#define DIN 512
#define DTRANK 16
#define BB 16
#define LL 512
#define TT (BB * LL)            // 8192 tokens
#define XZ_DIM (2 * DIN)        // 1024
#define DBC_DIM (DTRANK + 2 * DSTATE)  // 48
#define NCC 16                  // scan chunks
#define CHK (LL / NCC)          // 32
// pub entry (floats): [0,128) S_local, [128,2176) H_local[dloc*16+n], [2176,4224) H_incl
#define ESTR 4224

__device__ __forceinline__ unsigned short f2bf(float f) {
    union { float f; unsigned int u; } v; v.f = f;
    unsigned int r = v.u + 0x7fff + ((v.u >> 16) & 1);
    return (unsigned short)(r >> 16);
}
__device__ __forceinline__ float bf2f(unsigned short u) {
    union { unsigned int i; float f; } v; v.i = ((unsigned int)u) << 16;
    return v.f;
}
__device__ __forceinline__ float agload(const float* p) {
    return __hip_atomic_load(p, __ATOMIC_RELAXED, __HIP_MEMORY_SCOPE_AGENT);
}
__device__ __forceinline__ void agstore(float* p, float v) {
    __hip_atomic_store(p, v, __ATOMIC_RELAXED, __HIP_MEMORY_SCOPE_AGENT);
}

// ---------------- zero flags/tickets -----------------------------------------
__global__ __launch_bounds__(256) void zero_kernel(int* __restrict__ p, int n) {
    int i = blockIdx.x * 256 + threadIdx.x;
    if (i < n) p[i] = 0;
}

// ---------------- fp32 -> bf16 weight convert (all three, one dispatch) ------
__global__ __launch_bounds__(256) void cvt3_kernel(const float* __restrict__ s1,
                                                   unsigned short* __restrict__ d1, int n1,
                                                   const float* __restrict__ s2,
                                                   unsigned short* __restrict__ d2, int n2,
                                                   const float* __restrict__ s3,
                                                   unsigned short* __restrict__ d3, int n3) {
    int stride = gridDim.x * 256;
    for (int i = blockIdx.x * 256 + threadIdx.x; i < n1; i += stride) {
        float4 v = ((const float4*)s1)[i];
        ushort4 o; o.x = f2bf(v.x); o.y = f2bf(v.y); o.z = f2bf(v.z); o.w = f2bf(v.w);
        ((ushort4*)d1)[i] = o;
    }
    for (int i = blockIdx.x * 256 + threadIdx.x; i < n2; i += stride) {
        float4 v = ((const float4*)s2)[i];
        ushort4 o; o.x = f2bf(v.x); o.y = f2bf(v.y); o.z = f2bf(v.z); o.w = f2bf(v.w);
        ((ushort4*)d2)[i] = o;
    }
    for (int i = blockIdx.x * 256 + threadIdx.x; i < n3; i += stride) {
        float4 v = ((const float4*)s3)[i];
        ushort4 o; o.x = f2bf(v.x); o.y = f2bf(v.y); o.z = f2bf(v.z); o.w = f2bf(v.w);
        ((ushort4*)d3)[i] = o;
    }
}

// ---------------- LayerNorm -> bf16 ------------------------------------------
__global__ __launch_bounds__(256) void ln_kernel(const float* __restrict__ x,
                                                 const float* __restrict__ w,
                                                 const float* __restrict__ bvec,
                                                 unsigned short* __restrict__ out) {
    int t = blockIdx.x;
    int i = threadIdx.x;
    float v = x[t * DIMM + i];
    float s = v, s2 = v * v;
#pragma unroll
    for (int off = 1; off < 64; off <<= 1) {
        s  += __shfl_xor(s, off);
        s2 += __shfl_xor(s2, off);
    }
    __shared__ float ss[4], ss2[4];
    int wid = i >> 6;
    if ((i & 63) == 0) { ss[wid] = s; ss2[wid] = s2; }
    __syncthreads();
    s  = ss[0] + ss[1] + ss[2] + ss[3];
    s2 = ss2[0] + ss2[1] + ss2[2] + ss2[3];
    float mu  = s * (1.0f / DIMM);
    float var = s2 * (1.0f / DIMM) - mu * mu;
    float r   = rsqrtf(var + 1e-5f);
    out[t * DIMM + i] = f2bf((v - mu) * r * w[i] + bvec[i]);
}

// ---------------- bf16 MFMA NT GEMM (round-7 proven version) -----------------
// Mode A (C1b != null): bf16 outputs, cols < nsplit -> C1b, else C2b (ldc each).
// Mode B (C1b == null): fp32 C (+resid).
#define TBM 128
#define TBN 64
#define TBK 32
#define LDKW (TBK + 8)
__global__ __launch_bounds__(256) void gemm_bf16(const unsigned short* __restrict__ A, int lda,
                                                 const unsigned short* __restrict__ Bw, int ldb,
                                                 const float* __restrict__ bias,
                                                 const float* __restrict__ resid,
                                                 float* __restrict__ C,
                                                 unsigned short* __restrict__ C1b,
                                                 unsigned short* __restrict__ C2b, int nsplit,
                                                 int ldc, int N, int K) {
    using short8  = __attribute__((ext_vector_type(8))) short;
    using floatx4 = __attribute__((ext_vector_type(4))) float;
    __shared__ __align__(16) unsigned short As[TBM * LDKW];
    __shared__ __align__(16) unsigned short Bs[TBN * LDKW];

    int tid  = threadIdx.x;
    int m0   = blockIdx.y * TBM;
    int n0   = blockIdx.x * TBN;
    int w    = tid >> 6;
    int lane = tid & 63;
    int wm   = (w & 1) * 64;
    int wn   = (w >> 1) * 32;
    int lr   = lane & 15;
    int quad = lane >> 4;

    floatx4 acc[4][2] = {};

    int ar = tid >> 1;
    int ak = (tid & 1) * 16;
    int br = tid >> 2;
    int bk = (tid & 3) * 8;

    for (int k0 = 0; k0 < K; k0 += TBK) {
        {
            const unsigned short* src = &A[(size_t)(m0 + ar) * lda + k0 + ak];
            int4 a0 = *(const int4*)(src);
            int4 a1 = *(const int4*)(src + 8);
            *(int4*)&As[ar * LDKW + ak]     = a0;
            *(int4*)&As[ar * LDKW + ak + 8] = a1;
        }
        {
            int gn = n0 + br;
            int4 b0 = make_int4(0, 0, 0, 0);
            if (gn < N) b0 = *(const int4*)&Bw[(size_t)gn * ldb + k0 + bk];
            *(int4*)&Bs[br * LDKW + bk] = b0;
        }
        __syncthreads();
        short8 af[4], bf[2];
#pragma unroll
        for (int i = 0; i < 4; ++i)
            af[i] = *(const short8*)&As[(wm + i * 16 + lr) * LDKW + quad * 8];
#pragma unroll
        for (int j = 0; j < 2; ++j)
            bf[j] = *(const short8*)&Bs[(wn + j * 16 + lr) * LDKW + quad * 8];
#pragma unroll
        for (int i = 0; i < 4; ++i)
#pragma unroll
            for (int j = 0; j < 2; ++j)
                acc[i][j] = __builtin_amdgcn_mfma_f32_16x16x32_bf16(af[i], bf[j], acc[i][j], 0, 0, 0);
        __syncthreads();
    }

#pragma unroll
    for (int j = 0; j < 2; ++j) {
        int cn = n0 + wn + j * 16 + lr;
        if (cn < N) {
            float bb = bias ? bias[cn] : 0.0f;
            if (C1b) {
                unsigned short* dst = (cn < nsplit) ? C1b : C2b;
                int col = (cn < nsplit) ? cn : cn - nsplit;
#pragma unroll
                for (int i = 0; i < 4; ++i)
#pragma unroll
                    for (int r = 0; r < 4; ++r) {
                        int cm = m0 + wm + i * 16 + quad * 4 + r;
                        dst[(size_t)cm * ldc + col] = f2bf(acc[i][j][r] + bb);
                    }
            } else {
#pragma unroll
                for (int i = 0; i < 4; ++i)
#pragma unroll
                    for (int r = 0; r < 4; ++r) {
                        int cm = m0 + wm + i * 16 + quad * 4 + r;
                        float v = acc[i][j][r] + bb;
                        if (resid) v += resid[(size_t)cm * ldc + cn];
                        C[(size_t)cm * ldc + cn] = v;
                    }
            }
        }
    }
}

// ---------------- Depthwise causal conv (4-tap) + SiLU, bf16 in/out ----------
__global__ __launch_bounds__(256) void conv_silu(const unsigned short* __restrict__ Xb,
                                                 const float* __restrict__ cw,
                                                 const float* __restrict__ cb,
                                                 unsigned short* __restrict__ xcb) {
    int idx = blockIdx.x * blockDim.x + threadIdx.x;
    int d = idx & (DIN - 1);
    int t = idx >> 9;
    int l = t & (LL - 1);
    int bq = t >> 9;
    float acc = cb[d];
#pragma unroll
    for (int k = 0; k < DCONV; ++k) {
        int ls = l - (DCONV - 1) + k;
        if (ls >= 0) acc += cw[d * DCONV + k] * bf2f(Xb[(size_t)(bq * LL + ls) * DIN + d]);
    }
    float v = acc / (1.0f + __expf(-acc));
    xcb[(size_t)t * DIN + d] = f2bf(v);
}

// ---------------- dt = softplus(dbc[:, :16] @ dtw^T + dtb) -> bf16 -----------
__global__ __launch_bounds__(256) void dt_kernel(const float* __restrict__ dbc,
                                                 const float* __restrict__ dtw,
                                                 const float* __restrict__ dtbias,
                                                 unsigned short* __restrict__ dtout) {
    int idx = blockIdx.x * blockDim.x + threadIdx.x;  // over TT*DIN
    int d = idx & (DIN - 1);
    int t = idx >> 9;
    float a = dtbias[d];
    const float4* wv = (const float4*)(dtw + d * DTRANK);
    const float* dr = dbc + (size_t)t * DBC_DIM;
#pragma unroll
    for (int q = 0; q < 4; ++q) {
        float4 w4 = wv[q];
        a += w4.x * dr[q * 4 + 0] + w4.y * dr[q * 4 + 1] +
             w4.z * dr[q * 4 + 2] + w4.w * dr[q * 4 + 3];
    }
    float sp = (a > 20.0f) ? a : log1pf(__expf(a));
    dtout[(size_t)t * DIN + d] = f2bf(sp);
}

// ---------------- Fused selective scan: single pass + decoupled lookback -----
// 1024 blocks via ticket; ticket t -> c = t>>6, chain = t&63 (chain = b*4+dq).
// Block: 256 thr = 128 d x 2 state-halves (8 states each).
__global__ __launch_bounds__(256) void scan_fused(const unsigned short* __restrict__ xcb,
                                                  const unsigned short* __restrict__ dtb,
                                                  const unsigned short* __restrict__ Zb,
                                                  const float* __restrict__ dbc,
                                                  const float* __restrict__ A_log,
                                                  const float* __restrict__ Dp,
                                                  float* __restrict__ pub,
                                                  int* __restrict__ flags,
                                                  int* __restrict__ ticket,
                                                  unsigned short* __restrict__ gb) {
    __shared__ float LB[CHK * DBC_DIM];
    __shared__ int tkt_s;
    if (threadIdx.x == 0) tkt_s = atomicAdd(ticket, 1);
    __syncthreads();
    int t = tkt_s;
    int c = t >> 6;
    int chain = t & 63;
    int b  = chain >> 2;
    int dq = chain & 3;
    int dloc = threadIdx.x >> 1;
    int sh   = threadIdx.x & 1;
    int d  = dq * 128 + dloc;
    int n0 = sh * 8;
    int base = b * LL + c * CHK;

    for (int i = threadIdx.x; i < CHK * DBC_DIM / 4; i += 256)
        ((float4*)LB)[i] = ((const float4*)(dbc + (size_t)base * DBC_DIM))[i];

    float a[8];
    {
        const float4* ar = (const float4*)(A_log + d * DSTATE + n0);
        float4 v0 = ar[0], v1 = ar[1];
        a[0] = -__expf(v0.x); a[1] = -__expf(v0.y); a[2] = -__expf(v0.z); a[3] = -__expf(v0.w);
        a[4] = -__expf(v1.x); a[5] = -__expf(v1.y); a[6] = -__expf(v1.z); a[7] = -__expf(v1.w);
    }
    __syncthreads();

    // ---- pass 1: local scan from h=0 ----
    float h[8];
#pragma unroll
    for (int j = 0; j < 8; ++j) h[j] = 0.0f;
    float Ssum = 0.0f;
    float u   = bf2f(xcb[(size_t)base * DIN + d]);
    float dtv = bf2f(dtb[(size_t)base * DIN + d]);
#pragma unroll 4
    for (int s = 0; s < CHK; ++s) {
        float nu  = bf2f(xcb[(size_t)(base + s + 1) * DIN + d]);
        float ndt = bf2f(dtb[(size_t)(base + s + 1) * DIN + d]);
        const float* row = &LB[s * DBC_DIM];
        Ssum += dtv;
        float wv = dtv * u;
#pragma unroll
        for (int j = 0; j < 8; ++j) {
            float dA = __expf(dtv * a[j]);
            h[j] = dA * h[j] + wv * row[DTRANK + n0 + j];
        }
        u = nu; dtv = ndt;
    }

    float* ent = pub + (size_t)t * ESTR;
    int last = (c == NCC - 1);

    // ---- publish local (flag=1), only useful if someone may look past us ----
    if (!last && c > 0) {
        if (sh == 0) agstore(&ent[dloc], Ssum);
#pragma unroll
        for (int j = 0; j < 8; ++j) agstore(&ent[128 + dloc * 16 + n0 + j], h[j]);
        __threadfence();
        __syncthreads();
        if (threadIdx.x == 0)
            __hip_atomic_store(&flags[t], 1, __ATOMIC_RELEASE, __HIP_MEMORY_SCOPE_AGENT);
    }

    // ---- lookback: carry = combine of chunks 0..c-1 ----
    float carry[8];
    if (c == 0) {
#pragma unroll
        for (int j = 0; j < 8; ++j) carry[j] = 0.0f;
    } else {
        float accp[8], acch[8];
#pragma unroll
        for (int j = 0; j < 8; ++j) { accp[j] = 1.0f; acch[j] = 0.0f; }
        int cp = c - 1;
        while (true) {
            int fidx = (cp << 6) | chain;
            int fv;
            do {
                fv = __hip_atomic_load(&flags[fidx], __ATOMIC_ACQUIRE, __HIP_MEMORY_SCOPE_AGENT);
                if (fv == 0) __builtin_amdgcn_s_sleep(2);
            } while (fv == 0);
            const float* e = pub + (size_t)fidx * ESTR;
            if (fv == 2) {
#pragma unroll
                for (int j = 0; j < 8; ++j)
                    carry[j] = acch[j] + accp[j] * agload(&e[2176 + dloc * 16 + n0 + j]);
                break;
            } else {
                float Sc = agload(&e[dloc]);
#pragma unroll
                for (int j = 0; j < 8; ++j) {
                    acch[j] += accp[j] * agload(&e[128 + dloc * 16 + n0 + j]);
                    accp[j] *= __expf(a[j] * Sc);
                }
                --cp;
            }
        }
    }

    // ---- publish inclusive (flag=2) ----
    if (!last) {
#pragma unroll
        for (int j = 0; j < 8; ++j) {
            float hi = carry[j] * __expf(a[j] * Ssum) + h[j];
            agstore(&ent[2176 + dloc * 16 + n0 + j], hi);
        }
        __threadfence();
        __syncthreads();
        if (threadIdx.x == 0)
            __hip_atomic_store(&flags[t], 2, __ATOMIC_RELEASE, __HIP_MEMORY_SCOPE_AGENT);
    }

    // ---- pass 2: output scan with h0 = carry; fused g = y*silu(z) -> bf16 ----
    float Dd = Dp[d];
#pragma unroll
    for (int j = 0; j < 8; ++j) h[j] = carry[j];
    u   = bf2f(xcb[(size_t)base * DIN + d]);
    dtv = bf2f(dtb[(size_t)base * DIN + d]);
#pragma unroll 4
    for (int s = 0; s < CHK; ++s) {
        float nu  = bf2f(xcb[(size_t)(base + s + 1) * DIN + d]);
        float ndt = bf2f(dtb[(size_t)(base + s + 1) * DIN + d]);
        const float* row = &LB[s * DBC_DIM];
        float wv = dtv * u;
        float y  = (sh == 0) ? u * Dd : 0.0f;
#pragma unroll
        for (int j = 0; j < 8; ++j) {
            float dA = __expf(dtv * a[j]);
            h[j] = dA * h[j] + wv * row[DTRANK + n0 + j];
            y += h[j] * row[DTRANK + DSTATE + n0 + j];
        }
        y += __shfl_xor(y, 1);
        if (sh == 0) {
            float zf = bf2f(Zb[(size_t)(base + s) * DIN + d]);
            float g = y * (zf / (1.0f + __expf(-zf)));
            gb[(size_t)(base + s) * DIN + d] = f2bf(g);
        }
        u = nu; dtv = ndt;
    }
}

extern "C" void kernel_launch(void* const* d_in, const int* in_sizes, int n_in,
                              void* d_out, int out_size, void* d_ws, size_t ws_size,
                              hipStream_t stream) {
    const float* x_in   = (const float*)d_in[0];
    const float* ln_w   = (const float*)d_in[1];
    const float* ln_b   = (const float*)d_in[2];
    const float* in_w   = (const float*)d_in[3];
    const float* in_b   = (const float*)d_in[4];
    const float* conv_w = (const float*)d_in[5];
    const float* conv_b = (const float*)d_in[6];
    const float* xp_w   = (const float*)d_in[7];
    const float* dt_w   = (const float*)d_in[8];
    const float* dt_b   = (const float*)d_in[9];
    const float* A_log  = (const float*)d_in[10];
    const float* Dp     = (const float*)d_in[11];
    const float* ow     = (const float*)d_in[12];
    float* out = (float*)d_out;

    const size_t M = 1048576;
    float* ws = (float*)d_ws;
    float* xbuf = ws;                              // [0,2M) fp32 layer io
    unsigned short* hb  = (unsigned short*)(ws + 2 * M);   // [2M,3M) bf16 TT*256
    float* dbc = ws + 3 * M;                       // [3M,3.5M) fp32 TT*48
    unsigned short* Xb  = (unsigned short*)(ws + 4 * M);   // [4M,6M) bf16 TT*512
    unsigned short* Zb  = (unsigned short*)(ws + 6 * M);   // [6M,8M)
    unsigned short* xcb = (unsigned short*)(ws + 8 * M);   // [8M,10M)
    unsigned short* dtb = (unsigned short*)(ws + 10 * M);  // [10M,12M)
    unsigned short* gb  = (unsigned short*)(ws + 12 * M);  // [12M,14M)
    float* pub = ws + 14 * M;                      // [14M, 14M+1024*4224) ~ 18.13M
    int* flagsBase = (int*)(ws + 18 * M + 262144); // 4*1024 flags + 4 tickets
    unsigned short* inwb = (unsigned short*)(ws + 18 * M + 524288);
    unsigned short* owb  = inwb + (size_t)NB * XZ_DIM * DIMM;
    unsigned short* xpwb = owb + (size_t)NB * DIMM * DIN;

    zero_kernel<<<(4 * 1024 + 4 + 255) / 256, 256, 0, stream>>>(flagsBase, 4 * 1024 + 4);

    cvt3_kernel<<<256, 256, 0, stream>>>(
        in_w, inwb, NB * XZ_DIM * DIMM / 4,
        ow,   owb,  NB * DIMM * DIN / 4,
        xp_w, xpwb, NB * DBC_DIM * DIN / 4);

    for (int layer = 0; layer < NB; ++layer) {
        const float* xi = (layer == 0) ? x_in : xbuf;
        float* xo = (layer == NB - 1) ? out : xbuf;

        ln_kernel<<<TT, 256, 0, stream>>>(xi, ln_w + layer * DIMM, ln_b + layer * DIMM, hb);

        // in_proj: both halves bf16 (X -> Xb, Z -> Zb)
        gemm_bf16<<<dim3(XZ_DIM / TBN, TT / TBM), 256, 0, stream>>>(
            hb, DIMM, inwb + (size_t)layer * XZ_DIM * DIMM, DIMM,
            in_b + layer * XZ_DIM, nullptr, nullptr, Xb, Zb, DIN, DIN, XZ_DIM, DIMM);

        conv_silu<<<(TT * DIN) / 256, 256, 0, stream>>>(
            Xb, conv_w + layer * DIN * DCONV, conv_b + layer * DIN, xcb);

        // x_proj: bf16 MFMA -> dbc fp32
        gemm_bf16<<<dim3(1, TT / TBM), 256, 0, stream>>>(
            xcb, DIN, xpwb + (size_t)layer * DBC_DIM * DIN, DIN,
            nullptr, nullptr, dbc, nullptr, nullptr, 0, DBC_DIM, DBC_DIM, DIN);

        dt_kernel<<<(TT * DIN) / 256, 256, 0, stream>>>(
            dbc, dt_w + (size_t)layer * DIN * DTRANK, dt_b + layer * DIN, dtb);

        // fused scan (p1+p2+p3): 1024 ticket-ordered blocks
        scan_fused<<<BB * NCC * 4, 256, 0, stream>>>(
            xcb, dtb, Zb, dbc, A_log + (size_t)layer * DIN * DSTATE,
            Dp + layer * DIN, pub, flagsBase + layer * 1024,
            flagsBase + 4096 + layer, gb);

        // out_proj: fp32 out + residual
        gemm_bf16<<<dim3(DIMM / TBN, TT / TBM), 256, 0, stream>>>(
            gb, DIN, owb + (size_t)layer * DIMM * DIN, DIN,
            nullptr, xi, xo, nullptr, nullptr, 0, DIMM, DIMM, DIN);
    }
}

// Round 10
// 681.767 us; speedup vs baseline: 3.2565x; 3.2565x over previous
//
#include <hip/hip_runtime.h>
#include <math.h>

#define NB 4
#define DIMM 256
#define DSTATE 16
#define DCONV 4
#define DIN 512
#define DTRANK 16
#define BB 16
#define LL 512
#define TT (BB * LL)            // 8192 tokens
#define XZ_DIM (2 * DIN)        // 1024
#define DBC_DIM (DTRANK + 2 * DSTATE)  // 48
#define NC 32                   // scan chunks
#define CHUNK (LL / NC)         // 16

__device__ __forceinline__ unsigned short f2bf(float f) {
    union { float f; unsigned int u; } v; v.f = f;
    unsigned int r = v.u + 0x7fff + ((v.u >> 16) & 1);
    return (unsigned short)(r >> 16);
}
__device__ __forceinline__ float bf2f(unsigned short u) {
    union { unsigned int i; float f; } v; v.i = ((unsigned int)u) << 16;
    return v.f;
}

// ---------------- fp32 -> bf16 weight convert (all three, one dispatch) ------
__global__ __launch_bounds__(256) void cvt3_kernel(const float* __restrict__ s1,
                                                   unsigned short* __restrict__ d1, int n1,
                                                   const float* __restrict__ s2,
                                                   unsigned short* __restrict__ d2, int n2,
                                                   const float* __restrict__ s3,
                                                   unsigned short* __restrict__ d3, int n3) {
    int stride = gridDim.x * 256;
    for (int i = blockIdx.x * 256 + threadIdx.x; i < n1; i += stride) {
        float4 v = ((const float4*)s1)[i];
        ushort4 o; o.x = f2bf(v.x); o.y = f2bf(v.y); o.z = f2bf(v.z); o.w = f2bf(v.w);
        ((ushort4*)d1)[i] = o;
    }
    for (int i = blockIdx.x * 256 + threadIdx.x; i < n2; i += stride) {
        float4 v = ((const float4*)s2)[i];
        ushort4 o; o.x = f2bf(v.x); o.y = f2bf(v.y); o.z = f2bf(v.z); o.w = f2bf(v.w);
        ((ushort4*)d2)[i] = o;
    }
    for (int i = blockIdx.x * 256 + threadIdx.x; i < n3; i += stride) {
        float4 v = ((const float4*)s3)[i];
        ushort4 o; o.x = f2bf(v.x); o.y = f2bf(v.y); o.z = f2bf(v.z); o.w = f2bf(v.w);
        ((ushort4*)d3)[i] = o;
    }
}

// ---------------- LayerNorm -> bf16 ------------------------------------------
__global__ __launch_bounds__(256) void ln_kernel(const float* __restrict__ x,
                                                 const float* __restrict__ w,
                                                 const float* __restrict__ bvec,
                                                 unsigned short* __restrict__ out) {
    int t = blockIdx.x;
    int i = threadIdx.x;
    float v = x[t * DIMM + i];
    float s = v, s2 = v * v;
#pragma unroll
    for (int off = 1; off < 64; off <<= 1) {
        s  += __shfl_xor(s, off);
        s2 += __shfl_xor(s2, off);
    }
    __shared__ float ss[4], ss2[4];
    int wid = i >> 6;
    if ((i & 63) == 0) { ss[wid] = s; ss2[wid] = s2; }
    __syncthreads();
    s  = ss[0] + ss[1] + ss[2] + ss[3];
    s2 = ss2[0] + ss2[1] + ss2[2] + ss2[3];
    float mu  = s * (1.0f / DIMM);
    float var = s2 * (1.0f / DIMM) - mu * mu;
    float r   = rsqrtf(var + 1e-5f);
    out[t * DIMM + i] = f2bf((v - mu) * r * w[i] + bvec[i]);
}

// ---------------- 128x128 bf16 MFMA GEMM (in_proj), padded LDS ---------------
// 4 waves x 64x64 wave tiles; bf16 split outputs (cols < nsplit -> C1b else C2b).
#define GBM2 128
#define GBN2 128
#define GBK2 32
#define LDW2 (GBK2 + 8)   // 40 ushorts
__global__ __launch_bounds__(256) void gemm128(const unsigned short* __restrict__ A, int lda,
                                               const unsigned short* __restrict__ Bw, int ldb,
                                               const float* __restrict__ bias,
                                               unsigned short* __restrict__ C1b,
                                               unsigned short* __restrict__ C2b, int nsplit,
                                               int ldc, int K) {
    using short8  = __attribute__((ext_vector_type(8))) short;
    using floatx4 = __attribute__((ext_vector_type(4))) float;
    __shared__ __align__(16) unsigned short As[GBM2 * LDW2];
    __shared__ __align__(16) unsigned short Bs[GBN2 * LDW2];

    int tid  = threadIdx.x;
    int m0   = blockIdx.y * GBM2;
    int n0   = blockIdx.x * GBN2;
    int w    = tid >> 6;
    int lane = tid & 63;
    int wm   = (w & 1) * 64;
    int wn   = (w >> 1) * 64;
    int lr   = lane & 15;
    int quad = lane >> 4;

    floatx4 acc[4][4] = {};

    int ar = tid >> 1;            // 0..127
    int ak = (tid & 1) * 16;      // 0 or 16

    for (int k0 = 0; k0 < K; k0 += GBK2) {
        {
            const unsigned short* src = &A[(size_t)(m0 + ar) * lda + k0 + ak];
            int4 a0 = *(const int4*)(src);
            int4 a1 = *(const int4*)(src + 8);
            *(int4*)&As[ar * LDW2 + ak]     = a0;
            *(int4*)&As[ar * LDW2 + ak + 8] = a1;
        }
        {
            const unsigned short* src = &Bw[(size_t)(n0 + ar) * ldb + k0 + ak];
            int4 b0 = *(const int4*)(src);
            int4 b1 = *(const int4*)(src + 8);
            *(int4*)&Bs[ar * LDW2 + ak]     = b0;
            *(int4*)&Bs[ar * LDW2 + ak + 8] = b1;
        }
        __syncthreads();
        short8 af[4], bf[4];
#pragma unroll
        for (int i = 0; i < 4; ++i)
            af[i] = *(const short8*)&As[(wm + i * 16 + lr) * LDW2 + quad * 8];
#pragma unroll
        for (int j = 0; j < 4; ++j)
            bf[j] = *(const short8*)&Bs[(wn + j * 16 + lr) * LDW2 + quad * 8];
#pragma unroll
        for (int i = 0; i < 4; ++i)
#pragma unroll
            for (int j = 0; j < 4; ++j)
                acc[i][j] = __builtin_amdgcn_mfma_f32_16x16x32_bf16(af[i], bf[j], acc[i][j], 0, 0, 0);
        __syncthreads();
    }

#pragma unroll
    for (int j = 0; j < 4; ++j) {
        int cn = n0 + wn + j * 16 + lr;
        float bb = bias ? bias[cn] : 0.0f;
        unsigned short* dst = (cn < nsplit) ? C1b : C2b;
        int col = (cn < nsplit) ? cn : cn - nsplit;
#pragma unroll
        for (int i = 0; i < 4; ++i)
#pragma unroll
            for (int r = 0; r < 4; ++r) {
                int cm = m0 + wm + i * 16 + quad * 4 + r;
                dst[(size_t)cm * ldc + col] = f2bf(acc[i][j][r] + bb);
            }
    }
}

// ---------------- bf16 MFMA NT GEMM (generic, round-7 proven) ----------------
// Mode A (C1b != null): bf16 outputs, cols < nsplit -> C1b, else C2b (ldc each).
// Mode B (C1b == null): fp32 C (+resid).
#define TBM 128
#define TBN 64
#define TBK 32
#define LDKW (TBK + 8)
__global__ __launch_bounds__(256) void gemm_bf16(const unsigned short* __restrict__ A, int lda,
                                                 const unsigned short* __restrict__ Bw, int ldb,
                                                 const float* __restrict__ bias,
                                                 const float* __restrict__ resid,
                                                 float* __restrict__ C,
                                                 unsigned short* __restrict__ C1b,
                                                 unsigned short* __restrict__ C2b, int nsplit,
                                                 int ldc, int N, int K) {
    using short8  = __attribute__((ext_vector_type(8))) short;
    using floatx4 = __attribute__((ext_vector_type(4))) float;
    __shared__ __align__(16) unsigned short As[TBM * LDKW];
    __shared__ __align__(16) unsigned short Bs[TBN * LDKW];

    int tid  = threadIdx.x;
    int m0   = blockIdx.y * TBM;
    int n0   = blockIdx.x * TBN;
    int w    = tid >> 6;
    int lane = tid & 63;
    int wm   = (w & 1) * 64;
    int wn   = (w >> 1) * 32;
    int lr   = lane & 15;
    int quad = lane >> 4;

    floatx4 acc[4][2] = {};

    int ar = tid >> 1;
    int ak = (tid & 1) * 16;
    int br = tid >> 2;
    int bk = (tid & 3) * 8;

    for (int k0 = 0; k0 < K; k0 += TBK) {
        {
            const unsigned short* src = &A[(size_t)(m0 + ar) * lda + k0 + ak];
            int4 a0 = *(const int4*)(src);
            int4 a1 = *(const int4*)(src + 8);
            *(int4*)&As[ar * LDKW + ak]     = a0;
            *(int4*)&As[ar * LDKW + ak + 8] = a1;
        }
        {
            int gn = n0 + br;
            int4 b0 = make_int4(0, 0, 0, 0);
            if (gn < N) b0 = *(const int4*)&Bw[(size_t)gn * ldb + k0 + bk];
            *(int4*)&Bs[br * LDKW + bk] = b0;
        }
        __syncthreads();
        short8 af[4], bf[2];
#pragma unroll
        for (int i = 0; i < 4; ++i)
            af[i] = *(const short8*)&As[(wm + i * 16 + lr) * LDKW + quad * 8];
#pragma unroll
        for (int j = 0; j < 2; ++j)
            bf[j] = *(const short8*)&Bs[(wn + j * 16 + lr) * LDKW + quad * 8];
#pragma unroll
        for (int i = 0; i < 4; ++i)
#pragma unroll
            for (int j = 0; j < 2; ++j)
                acc[i][j] = __builtin_amdgcn_mfma_f32_16x16x32_bf16(af[i], bf[j], acc[i][j], 0, 0, 0);
        __syncthreads();
    }

#pragma unroll
    for (int j = 0; j < 2; ++j) {
        int cn = n0 + wn + j * 16 + lr;
        if (cn < N) {
            float bb = bias ? bias[cn] : 0.0f;
            if (C1b) {
                unsigned short* dst = (cn < nsplit) ? C1b : C2b;
                int col = (cn < nsplit) ? cn : cn - nsplit;
#pragma unroll
                for (int i = 0; i < 4; ++i)
#pragma unroll
                    for (int r = 0; r < 4; ++r) {
                        int cm = m0 + wm + i * 16 + quad * 4 + r;
                        dst[(size_t)cm * ldc + col] = f2bf(acc[i][j][r] + bb);
                    }
            } else {
#pragma unroll
                for (int i = 0; i < 4; ++i)
#pragma unroll
                    for (int r = 0; r < 4; ++r) {
                        int cm = m0 + wm + i * 16 + quad * 4 + r;
                        float v = acc[i][j][r] + bb;
                        if (resid) v += resid[(size_t)cm * ldc + cn];
                        C[(size_t)cm * ldc + cn] = v;
                    }
            }
        }
    }
}

// ---------------- Depthwise causal conv (4-tap) + SiLU, bf16 in/out ----------
__global__ __launch_bounds__(256) void conv_silu(const unsigned short* __restrict__ Xb,
                                                 const float* __restrict__ cw,
                                                 const float* __restrict__ cb,
                                                 unsigned short* __restrict__ xcb) {
    int idx = blockIdx.x * blockDim.x + threadIdx.x;
    int d = idx & (DIN - 1);
    int t = idx >> 9;
    int l = t & (LL - 1);
    int bq = t >> 9;
    float acc = cb[d];
#pragma unroll
    for (int k = 0; k < DCONV; ++k) {
        int ls = l - (DCONV - 1) + k;
        if (ls >= 0) acc += cw[d * DCONV + k] * bf2f(Xb[(size_t)(bq * LL + ls) * DIN + d]);
    }
    float v = acc / (1.0f + __expf(-acc));
    xcb[(size_t)t * DIN + d] = f2bf(v);
}

// ---------------- dt = softplus(dbc[:, :16] @ dtw^T + dtb) -> bf16 -----------
__global__ __launch_bounds__(256) void dt_kernel(const float* __restrict__ dbc,
                                                 const float* __restrict__ dtw,
                                                 const float* __restrict__ dtbias,
                                                 unsigned short* __restrict__ dtout) {
    int idx = blockIdx.x * blockDim.x + threadIdx.x;  // over TT*DIN
    int d = idx & (DIN - 1);
    int t = idx >> 9;
    float a = dtbias[d];
    const float4* wv = (const float4*)(dtw + d * DTRANK);
    const float* dr = dbc + (size_t)t * DBC_DIM;
#pragma unroll
    for (int q = 0; q < 4; ++q) {
        float4 w4 = wv[q];
        a += w4.x * dr[q * 4 + 0] + w4.y * dr[q * 4 + 1] +
             w4.z * dr[q * 4 + 2] + w4.w * dr[q * 4 + 3];
    }
    float sp = (a > 20.0f) ? a : log1pf(__expf(a));
    dtout[(size_t)t * DIN + d] = f2bf(sp);
}

// ---------------- Selective scan: state-split (2 thr/d, 8 states each) -------
// grid = BB*NC*4 blocks; block covers 128 d x 2 state-halves; CHUNK=16 steps.
// H layout: [sc][d][16].
__global__ __launch_bounds__(256) void scan_p1(const unsigned short* __restrict__ xcb,
                                               const unsigned short* __restrict__ dtb,
                                               const float* __restrict__ dbc,
                                               const float* __restrict__ A_log,
                                               float* __restrict__ S,
                                               float* __restrict__ H) {
    int bid = blockIdx.x;
    int dq = bid & 3;
    int c  = (bid >> 2) & (NC - 1);
    int b  = bid >> 7;
    int dloc = threadIdx.x >> 1;
    int sh   = threadIdx.x & 1;
    int d  = dq * 128 + dloc;
    int n0 = sh * 8;
    int base = b * LL + c * CHUNK;

    __shared__ float LB[CHUNK * DBC_DIM];
    for (int i = threadIdx.x; i < CHUNK * DBC_DIM / 4; i += 256)
        ((float4*)LB)[i] = ((const float4*)(dbc + (size_t)base * DBC_DIM))[i];

    float a[8];
    {
        const float4* ar = (const float4*)(A_log + d * DSTATE + n0);
        float4 v0 = ar[0], v1 = ar[1];
        a[0] = -__expf(v0.x); a[1] = -__expf(v0.y); a[2] = -__expf(v0.z); a[3] = -__expf(v0.w);
        a[4] = -__expf(v1.x); a[5] = -__expf(v1.y); a[6] = -__expf(v1.z); a[7] = -__expf(v1.w);
    }
    __syncthreads();

    float h[8];
#pragma unroll
    for (int j = 0; j < 8; ++j) h[j] = 0.0f;
    float Ssum = 0.0f;
    float u   = bf2f(xcb[(size_t)base * DIN + d]);
    float dtv = bf2f(dtb[(size_t)base * DIN + d]);
#pragma unroll 4
    for (int s = 0; s < CHUNK; ++s) {
        float nu  = bf2f(xcb[(size_t)(base + s + 1) * DIN + d]);
        float ndt = bf2f(dtb[(size_t)(base + s + 1) * DIN + d]);
        const float* row = &LB[s * DBC_DIM];
        float4 b0 = *(const float4*)&row[DTRANK + n0];
        float4 b1 = *(const float4*)&row[DTRANK + n0 + 4];
        const float btv[8] = {b0.x, b0.y, b0.z, b0.w, b1.x, b1.y, b1.z, b1.w};
        Ssum += dtv;
        float wv = dtv * u;
#pragma unroll
        for (int j = 0; j < 8; ++j) {
            float dA = __expf(dtv * a[j]);
            h[j] = dA * h[j] + wv * btv[j];
        }
        u = nu; dtv = ndt;
    }
    size_t sc = (size_t)b * NC + c;
    if (sh == 0) S[sc * DIN + d] = Ssum;
#pragma unroll
    for (int j = 0; j < 8; ++j) H[(sc * DIN + d) * 16 + n0 + j] = h[j];
}

// Phase2: thread per (b,d,n); serial over chunks; Hin overwrites H in place.
__global__ __launch_bounds__(256) void scan_p2(const float* __restrict__ A_log,
                                               const float* __restrict__ S,
                                               float* __restrict__ H) {
    int idx = blockIdx.x * 256 + threadIdx.x;   // BB*DIN*16
    int n = idx & 15;
    int d = (idx >> 4) & (DIN - 1);
    int b = idx >> 13;
    float a = -__expf(A_log[d * DSTATE + n]);
    float h = 0.0f;
#pragma unroll
    for (int c = 0; c < NC; ++c) {
        size_t sc = (size_t)b * NC + c;
        float Sv = S[sc * DIN + d];
        size_t q = (sc * DIN + d) * 16 + n;
        float Hc = H[q];
        H[q] = h;
        h = __expf(a * Sv) * h + Hc;
    }
}

// Phase3: state-split scan; fused y + g = y*silu(z) -> bf16.
__global__ __launch_bounds__(256) void scan_p3(const unsigned short* __restrict__ xcb,
                                               const unsigned short* __restrict__ dtb,
                                               const unsigned short* __restrict__ Zb,
                                               const float* __restrict__ dbc,
                                               const float* __restrict__ A_log,
                                               const float* __restrict__ Dp,
                                               const float* __restrict__ Hin,
                                               unsigned short* __restrict__ gb) {
    int bid = blockIdx.x;
    int dq = bid & 3;
    int c  = (bid >> 2) & (NC - 1);
    int b  = bid >> 7;
    int dloc = threadIdx.x >> 1;
    int sh   = threadIdx.x & 1;
    int d  = dq * 128 + dloc;
    int n0 = sh * 8;
    int base = b * LL + c * CHUNK;

    __shared__ float LB[CHUNK * DBC_DIM];
    for (int i = threadIdx.x; i < CHUNK * DBC_DIM / 4; i += 256)
        ((float4*)LB)[i] = ((const float4*)(dbc + (size_t)base * DBC_DIM))[i];

    float a[8];
    {
        const float4* ar = (const float4*)(A_log + d * DSTATE + n0);
        float4 v0 = ar[0], v1 = ar[1];
        a[0] = -__expf(v0.x); a[1] = -__expf(v0.y); a[2] = -__expf(v0.z); a[3] = -__expf(v0.w);
        a[4] = -__expf(v1.x); a[5] = -__expf(v1.y); a[6] = -__expf(v1.z); a[7] = -__expf(v1.w);
    }
    float Dd = Dp[d];
    size_t sc = (size_t)b * NC + c;
    float h[8];
#pragma unroll
    for (int j = 0; j < 8; ++j) h[j] = Hin[(sc * DIN + d) * 16 + n0 + j];
    __syncthreads();

    float u   = bf2f(xcb[(size_t)base * DIN + d]);
    float dtv = bf2f(dtb[(size_t)base * DIN + d]);
#pragma unroll 4
    for (int s = 0; s < CHUNK; ++s) {
        float nu  = bf2f(xcb[(size_t)(base + s + 1) * DIN + d]);
        float ndt = bf2f(dtb[(size_t)(base + s + 1) * DIN + d]);
        const float* row = &LB[s * DBC_DIM];
        float4 b0 = *(const float4*)&row[DTRANK + n0];
        float4 b1 = *(const float4*)&row[DTRANK + n0 + 4];
        float4 c0 = *(const float4*)&row[DTRANK + DSTATE + n0];
        float4 c1 = *(const float4*)&row[DTRANK + DSTATE + n0 + 4];
        const float btv[8] = {b0.x, b0.y, b0.z, b0.w, b1.x, b1.y, b1.z, b1.w};
        const float ctv[8] = {c0.x, c0.y, c0.z, c0.w, c1.x, c1.y, c1.z, c1.w};
        float wv = dtv * u;
        float y  = (sh == 0) ? u * Dd : 0.0f;
#pragma unroll
        for (int j = 0; j < 8; ++j) {
            float dA = __expf(dtv * a[j]);
            h[j] = dA * h[j] + wv * btv[j];
            y += h[j] * ctv[j];
        }
        y += __shfl_xor(y, 1);
        if (sh == 0) {
            float zf = bf2f(Zb[(size_t)(base + s) * DIN + d]);
            float g = y * (zf / (1.0f + __expf(-zf)));
            gb[(size_t)(base + s) * DIN + d] = f2bf(g);
        }
        u = nu; dtv = ndt;
    }
}

extern "C" void kernel_launch(void* const* d_in, const int* in_sizes, int n_in,
                              void* d_out, int out_size, void* d_ws, size_t ws_size,
                              hipStream_t stream) {
    const float* x_in   = (const float*)d_in[0];
    const float* ln_w   = (const float*)d_in[1];
    const float* ln_b   = (const float*)d_in[2];
    const float* in_w   = (const float*)d_in[3];
    const float* in_b   = (const float*)d_in[4];
    const float* conv_w = (const float*)d_in[5];
    const float* conv_b = (const float*)d_in[6];
    const float* xp_w   = (const float*)d_in[7];
    const float* dt_w   = (const float*)d_in[8];
    const float* dt_b   = (const float*)d_in[9];
    const float* A_log  = (const float*)d_in[10];
    const float* Dp     = (const float*)d_in[11];
    const float* ow     = (const float*)d_in[12];
    float* out = (float*)d_out;

    const size_t M = 1048576;
    float* ws = (float*)d_ws;
    float* xbuf = ws;                              // [0,2M) fp32 layer io
    unsigned short* hb  = (unsigned short*)(ws + 2 * M);   // [2M,3M) bf16 TT*256
    float* dbc = ws + 3 * M;                       // [3M,3.5M) fp32 TT*48
    unsigned short* Xb  = (unsigned short*)(ws + 4 * M);   // [4M,6M) bf16 TT*512
    unsigned short* Zb  = (unsigned short*)(ws + 6 * M);   // [6M,8M)
    unsigned short* xcb = (unsigned short*)(ws + 8 * M);   // [8M,10M)
    unsigned short* dtb = (unsigned short*)(ws + 10 * M);  // [10M,12M)
    unsigned short* gb  = (unsigned short*)(ws + 12 * M);  // [12M,14M)
    float* Hbuf = ws + 14 * M;                     // [14M,18M) BB*NC*DIN*16 = 4M
    float* Sbuf = ws + 18 * M;                     // [18M,18.25M)
    unsigned short* inwb = (unsigned short*)(ws + 18 * M + 262144);
    unsigned short* owb  = inwb + (size_t)NB * XZ_DIM * DIMM;
    unsigned short* xpwb = owb + (size_t)NB * DIMM * DIN;

    cvt3_kernel<<<256, 256, 0, stream>>>(
        in_w, inwb, NB * XZ_DIM * DIMM / 4,
        ow,   owb,  NB * DIMM * DIN / 4,
        xp_w, xpwb, NB * DBC_DIM * DIN / 4);

    for (int layer = 0; layer < NB; ++layer) {
        const float* xi = (layer == 0) ? x_in : xbuf;
        float* xo = (layer == NB - 1) ? out : xbuf;

        ln_kernel<<<TT, 256, 0, stream>>>(xi, ln_w + layer * DIMM, ln_b + layer * DIMM, hb);

        // in_proj: both halves bf16 (X -> Xb, Z -> Zb), 128x128 tiles
        gemm128<<<dim3(XZ_DIM / GBN2, TT / GBM2), 256, 0, stream>>>(
            hb, DIMM, inwb + (size_t)layer * XZ_DIM * DIMM, DIMM,
            in_b + layer * XZ_DIM, Xb, Zb, DIN, DIN, DIMM);

        conv_silu<<<(TT * DIN) / 256, 256, 0, stream>>>(
            Xb, conv_w + layer * DIN * DCONV, conv_b + layer * DIN, xcb);

        // x_proj: bf16 MFMA -> dbc fp32
        gemm_bf16<<<dim3(1, TT / TBM), 256, 0, stream>>>(
            xcb, DIN, xpwb + (size_t)layer * DBC_DIM * DIN, DIN,
            nullptr, nullptr, dbc, nullptr, nullptr, 0, DBC_DIM, DBC_DIM, DIN);

        dt_kernel<<<(TT * DIN) / 256, 256, 0, stream>>>(
            dbc, dt_w + (size_t)layer * DIN * DTRANK, dt_b + layer * DIN, dtb);

        const float* Al = A_log + (size_t)layer * DIN * DSTATE;
        scan_p1<<<BB * NC * 4, 256, 0, stream>>>(xcb, dtb, dbc, Al, Sbuf, Hbuf);
        scan_p2<<<(BB * DIN * 16) / 256, 256, 0, stream>>>(Al, Sbuf, Hbuf);
        scan_p3<<<BB * NC * 4, 256, 0, stream>>>(xcb, dtb, Zb, dbc, Al,
                                                 Dp + layer * DIN, Hbuf, gb);

        // out_proj: fp32 out + residual
        gemm_bf16<<<dim3(DIMM / TBN, TT / TBM), 256, 0, stream>>>(
            gb, DIN, owb + (size_t)layer * DIMM * DIN, DIN,
            nullptr, xi, xo, nullptr, nullptr, 0, DIMM, DIMM, DIN);
    }
}